// Round 5
// baseline (127.456 us; speedup 1.0000x reference)
//
#include <hip/hip_runtime.h>

// cvmm: out[m] = x[m] @ w[sel[m]]
// x: [M,64] f32, sel: [M] i32, w: [8,64,64] f32, out: [M,64] f32
//
// R10: global_load_lds direct staging. R5-R9 (masked-pinned, sorted one-shot,
// persistent pipelined, obuf full-line stores) ALL land at 40-44us, <15% on
// every pipe: the invariant is the global->VGPR->cvt->ds_write staging chain,
// which the compiler keeps serializing (R6 sank the loads; R7/R9 eat a vmcnt
// wait per stage). This version removes the chain entirely:
//  - x staged f32 by DMA (__builtin_amdgcn_global_load_lds, 16B): LDS dest is
//    wave-uniform base + lane*16 (linear); the PERMUTE (token->sorted slot)
//    and the 32B-chunk XOR swizzle are applied to the per-lane GLOBAL source
//    address (HK m173 pattern). Full 256B token rows covered per DMA -> full
//    HBM lines, perfectly coalesced.
//  - compute reads STATIC slot rows (conflict-free swizzled), converts f32->
//    bf16 at fragment read; masked skip-loop MFMA over pinned W frags
//    (verified R5-R9 layout); acc stays in 32 VGPRs.
//  - xls REUSED as out staging after compute (no obuf): acc written back at
//    original token rows (swizzled), streamed out as 1KB-contiguous dwordx4.
//  - no wpack dispatch (W gathered in-kernel, L2-hot), no d_ws.
// LDS 33KB + ~90 VGPR -> 4 blocks/CU (16 waves). One __syncthreads (the DMA
// vmcnt fence) + 3 lgkm-only raw barriers.

typedef __bf16 bf16x8 __attribute__((ext_vector_type(8)));
typedef float  floatx4 __attribute__((ext_vector_type(4)));

#define CT 128   // tokens per block

#define GLOAD_LDS16(g, l)                                        \
    __builtin_amdgcn_global_load_lds(                            \
        (const __attribute__((address_space(1))) void*)(g),      \
        (__attribute__((address_space(3))) void*)(l), 16, 0, 0)

// lgkm-only barrier: global (DMA/W) loads stay in flight.
#define BARL() do {                                        \
    __builtin_amdgcn_sched_barrier(0);                     \
    asm volatile("s_waitcnt lgkmcnt(0)" ::: "memory");     \
    __builtin_amdgcn_s_barrier();                          \
    __builtin_amdgcn_sched_barrier(0);                     \
} while (0)

__global__ __launch_bounds__(256, 4) void cvmm_kernel(
    const float* __restrict__ x,
    const int* __restrict__ sel,
    const float* __restrict__ w,
    float* __restrict__ out)
{
    // x tile: 128 rows x 256B f32. 32B chunks XOR-swizzled by row:
    //   logical chunk c of row r lives at phys chunk p = c ^ (r&7).
    // Phase 1 rows = sorted slots; phase 2 (out staging) rows = orig tokens.
    __shared__ __align__(16) unsigned char xls[CT * 256];   // 32 KB
    __shared__ unsigned int sortLds[CT];                    // slot -> tok|e<<8

    const int T    = threadIdx.x;
    const int lane = T & 63;
    const int wv   = T >> 6;     // 0..3 -> n-tile
    const int q    = lane >> 4;  // 0..3
    const int l16  = lane & 15;
    const int n0   = wv << 4;

    const long tok0 = (long)blockIdx.x * CT;

    // ---- 1) sel + stable expert sort (wave 0; 2 tokens/lane, in-register)
    if (wv == 0) {
        const int s0 = sel[tok0 + lane];
        const int s1 = sel[tok0 + 64 + lane];
        const unsigned long long lt = (1ull << lane) - 1;
        int slot0 = 0, slot1 = 0, pref = 0;
#pragma unroll
        for (int e = 0; e < 8; ++e) {
            unsigned long long m0 = __ballot(s0 == e);
            unsigned long long m1 = __ballot(s1 == e);
            if (s0 == e) slot0 = pref + __popcll(m0 & lt);
            if (s1 == e) slot1 = pref + __popcll(m0) + __popcll(m1 & lt);
            pref += __popcll(m0) + __popcll(m1);
        }
        sortLds[slot0] = (unsigned)lane        | ((unsigned)s0 << 8);
        sortLds[slot1] = (unsigned)(64 + lane) | ((unsigned)s1 << 8);
    }

    // ---- 2) W fragment gather (all waves; strided scalar, L2-hot after the
    //         first blocks). frag (e,t): f[j] = w[e][t*32+q*8+j][n0+l16].
    floatx4 bfp[8][2];
#pragma unroll
    for (int e = 0; e < 8; ++e)
#pragma unroll
        for (int t = 0; t < 2; ++t) {
            const float* ws = w + ((e * 64 + t * 32 + q * 8) * 64) + (n0 + l16);
            bf16x8 f;
#pragma unroll
            for (int j = 0; j < 8; ++j) f[j] = (__bf16)ws[j * 64];
            bfp[e][t] = __builtin_bit_cast(floatx4, f);
        }

    BARL();   // sortLds visible; W/sel loads NOT drained

    // ---- 3) DMA x -> LDS: slot-ordered rows, pre-swizzled global source.
    //         Issue i of wave wv covers slot rows [i*16+wv*4, +4); lane L
    //         lands at phys granule L&15 of row i*16+wv*4+(L>>4).
    int tokA[8];
#pragma unroll
    for (int i = 0; i < 8; ++i) {
        const int r    = i * 16 + wv * 4 + (lane >> 4);
        const int tokR = (int)(sortLds[r] & 255u);
        const int p    = (lane & 15) >> 1;       // phys 32B chunk
        const int c    = p ^ (r & 7);            // logical 32B chunk
        const float* g = x + (tok0 + tokR) * 64 + c * 8 + (lane & 1) * 4;
        GLOAD_LDS16(g, xls + i * 4096 + wv * 1024);
    }

    // read compute-side metadata while DMA is in flight
#pragma unroll
    for (int i = 0; i < 8; ++i)
        tokA[i] = (int)sortLds[i * 16 + l16];

    // pin W frags here: the forced vmcnt wait merges into syncthreads' drain
#pragma unroll
    for (int e = 0; e < 8; ++e)
        asm volatile("" : "+v"(bfp[e][0]), "+v"(bfp[e][1]));

    __syncthreads();   // vmcnt(0)+lgkmcnt(0): the DMA completion fence

    // ---- 4) compute 8 m-tiles; static slot rows; acc stays in registers
    bf16x8 zf;
#pragma unroll
    for (int j = 0; j < 8; ++j) zf[j] = (__bf16)0.0f;

    floatx4 acc[8];
#pragma unroll
    for (int i = 0; i < 8; ++i) {
        const int el = tokA[i] >> 8;
        const int r  = i * 16 + l16;
        const int pA = (q)     ^ (r & 7);
        const int pB = (q + 4) ^ (r & 7);
        const float* fa = (const float*)(xls + r * 256 + pA * 32);
        const float* fb = (const float*)(xls + r * 256 + pB * 32);
        const floatx4 a0 = *(const floatx4*)(fa);
        const floatx4 a1 = *(const floatx4*)(fa + 4);
        const floatx4 b0 = *(const floatx4*)(fb);
        const floatx4 b1 = *(const floatx4*)(fb + 4);
        bf16x8 af0, af1;
#pragma unroll
        for (int j = 0; j < 4; ++j) {
            af0[j] = (__bf16)a0[j]; af0[j + 4] = (__bf16)a1[j];
            af1[j] = (__bf16)b0[j]; af1[j + 4] = (__bf16)b1[j];
        }
        const int elo = __builtin_amdgcn_readfirstlane(el);
        const int ehi = __builtin_amdgcn_readlane(el, 15);

        floatx4 a = {0.0f, 0.0f, 0.0f, 0.0f};
#pragma unroll
        for (int e = 0; e < 8; ++e) {
            if (e >= elo && e <= ehi) {          // wave-uniform guard
                const bool ok = (el == e);       // per-lane (boundary only)
                a = __builtin_amdgcn_mfma_f32_16x16x32_bf16(
                        __builtin_bit_cast(bf16x8, bfp[e][0]),
                        ok ? af0 : zf, a, 0, 0, 0);
                a = __builtin_amdgcn_mfma_f32_16x16x32_bf16(
                        __builtin_bit_cast(bf16x8, bfp[e][1]),
                        ok ? af1 : zf, a, 0, 0, 0);
            }
        }
        acc[i] = a;
    }

    BARL();   // all xls reads done -> safe to overwrite as out staging

    // ---- 5) acc -> xls at ORIGINAL token rows (swizzled granules).
    //         lane (wv,q,l16) tile i holds out[tok][n0+4q..+3] = granule
    //         g = wv*4+q of row tok.
    {
        const int g  = wv * 4 + q;
        const int gh = (g & 1) * 16;
        const int gc = g >> 1;
#pragma unroll
        for (int i = 0; i < 8; ++i) {
            const int tokL = tokA[i] & 255;
            *(floatx4*)(xls + tokL * 256 + ((gc ^ (tokL & 7)) << 5) + gh) = acc[i];
        }
    }

    BARL();

    // ---- 6) stream xls -> out: lane-linear, 1KB contiguous per wave instr
    {
        float* og = out + tok0 * 64;
#pragma unroll
        for (int i = 0; i < 8; ++i) {
            const int G = i * 256 + T;           // granule id 0..2047
            const int r = G >> 4, g = G & 15;
            const floatx4 v = *(const floatx4*)(
                xls + r * 256 + ((((g >> 1) ^ (r & 7))) << 5) + (g & 1) * 16);
            *(floatx4*)(og + (long)G * 4) = v;
        }
    }
}

extern "C" void kernel_launch(void* const* d_in, const int* in_sizes, int n_in,
                              void* d_out, int out_size, void* d_ws, size_t ws_size,
                              hipStream_t stream) {
    const float* x   = (const float*)d_in[0];
    const int*   sel = (const int*)d_in[1];
    const float* w   = (const float*)d_in[2];
    float*       out = (float*)d_out;

    const int M = in_sizes[0] / 64;                 // 262144
    cvmm_kernel<<<M / CT, 256, 0, stream>>>(x, sel, w, out);
}